// Round 14
// baseline (192.121 us; speedup 1.0000x reference)
//
#include <hip/hip_runtime.h>

#define DIM     256
#define HW      1024
#define N_ROWS  65536
#define NT      256
#define QBM     32
#define NBLK    2048
#define MARGIN  0.25f

#define OUT_Q_OFF    16777216
#define OUT_LOSS_OFF 16842752

// ws: floats [0,512) c2 ; [512,2560) dist partials(2048) ; [2560,4608) x2 partials(2048)
// int [4608] flag count ; ints [5120, 70656) flagged-row list
// bytes [524288, 786432) lut fp16 fragment-linear (256KB)
#define WS_DIST   512
#define WS_X2     2560
#define WS_CNT_I  4608
#define WS_LIST_I 5120
#define WS_LUTH_B 524288

#define VQ_LDS 49152   // 32KB B + 16KB A

typedef _Float16 half8v __attribute__((ext_vector_type(8)));
typedef float floatx4 __attribute__((ext_vector_type(4)));

#define GLOAD_LDS16(gaddr, laddr) \
    __builtin_amdgcn_global_load_lds((const __attribute__((address_space(1))) unsigned int*)(gaddr), \
                                     (__attribute__((address_space(3))) unsigned int*)(laddr), 16, 0, 0)

__global__ void c2_kernel(const float* __restrict__ lut, float* __restrict__ ws) {
    if (threadIdx.x == 0) ((int*)ws)[WS_CNT_I] = 0;
    int t = threadIdx.x;
    for (int k = t; k < 512; k += 256) {
        const float4* row = (const float4*)(lut + (size_t)k * DIM);
        float s = 0.f;
        #pragma unroll 8
        for (int i = 0; i < DIM / 4; ++i) {
            float4 v = row[i];
            s += v.x * v.x + v.y * v.y + v.z * v.z + v.w * v.w;
        }
        ws[k] = s;
    }
}

// lut -> fp16, fragment-linear: chunk(dc*32+ctu)*1KB + lane*16B
// lane l holds code ctu*16+(l&15), d = dc*32+(l>>4)*8 .. +7
__global__ void lutprep_kernel(const float* __restrict__ lut, float* __restrict__ ws) {
    int g = blockIdx.x * 256 + threadIdx.x;    // 0..16383
    int lane = g & 63;
    int ctu  = (g >> 6) & 31;
    int dcg  = g >> 11;
    int code = ctu * 16 + (lane & 15);
    int d0   = dcg * 32 + (lane >> 4) * 8;
    const float* src = lut + (size_t)code * DIM + d0;
    half8v h;
    #pragma unroll
    for (int j = 0; j < 8; ++j) h[j] = (_Float16)src[j];
    char* dst = (char*)ws + WS_LUTH_B + (size_t)(dcg * 32 + ctu) * 1024 + lane * 16;
    *(half8v*)dst = h;
}

__global__ __launch_bounds__(NT, 3) void vq_kernel(const float* __restrict__ x,
                                                   const float* __restrict__ lut,
                                                   float* __restrict__ out,
                                                   float* __restrict__ ws) {
    extern __shared__ char smem[];
    // smem[0,32768): B buffer, 32 chunks: (cg*8+ct)*1024 + lane*16
    // smem[32768,49152): A buffer, chunks (rtl*8+dc)*1024 + lane*16

    const char* luth = (const char*)ws + WS_LUTH_B;
    char* asm_ = smem + 32768;

    const int tid = threadIdx.x;
    const int blk = blockIdx.x;
    const int n0  = blk * QBM;
    const int b   = n0 >> 10;
    const int hw0 = n0 & 1023;
    const float* xb = x + (size_t)b * (DIM * HW) + hw0;

    const int wave = tid >> 6;   // = cg code quarter
    const int lane = tid & 63;
    const int l15  = lane & 15;
    const int l4   = lane >> 4;
    const int cg   = wave;

    // ---- stage A ONCE: 32 rows x 256 d -> fp16 fragment-linear ----
    float x2local = 0.f;
    {
        const int srow = tid & 31;       // row
        const int sdg  = tid >> 5;       // d-group (=dc) 0..7
        const float* src = xb + (size_t)(sdg * 32) * HW + srow;
        char* abase = asm_ + (size_t)((srow >> 4) * 8 + sdg) * 1024 + (srow & 15) * 16;
        #pragma unroll
        for (int eg = 0; eg < 4; ++eg) {
            half8v h;
            #pragma unroll
            for (int j = 0; j < 8; ++j) {
                float v = src[(size_t)(eg * 8 + j) * HW];
                x2local = fmaf(v, v, x2local);
                h[j] = (_Float16)v;
            }
            *(half8v*)(abase + eg * 256) = h;   // lane slot (srow&15)+eg*16 -> byte ((srow&15)+eg*16)*16
        }
    }

    floatx4 acc[2][8];
    #pragma unroll
    for (int i = 0; i < 2; ++i)
        #pragma unroll
        for (int j = 0; j < 8; ++j) acc[i][j] = (floatx4)0.f;

    for (int dc = 0; dc < 8; ++dc) {
        __syncthreads();   // prior B reads done (dc=0: publishes A)
        // ---- DMA B[dc]: 32 chunks, wave w stages chunks w*8..w*8+7 ----
        #pragma unroll
        for (int i = 0; i < 8; ++i) {
            int cc = wave * 8 + i;
            GLOAD_LDS16(luth + (size_t)(dc * 32 + cc) * 1024 + lane * 16, smem + cc * 1024);
        }
        __syncthreads();   // DMA landed
        // ---- frags ----
        half8v ah[2], bh[8];
        #pragma unroll
        for (int rtl = 0; rtl < 2; ++rtl)
            ah[rtl] = *(const half8v*)(asm_ + (size_t)(rtl * 8 + dc) * 1024 + lane * 16);
        #pragma unroll
        for (int ct = 0; ct < 8; ++ct)
            bh[ct] = *(const half8v*)(smem + (size_t)(cg * 8 + ct) * 1024 + lane * 16);
        // ---- 16 MFMAs ----
        #pragma unroll
        for (int ct = 0; ct < 8; ++ct)
            #pragma unroll
            for (int rtl = 0; rtl < 2; ++rtl)
                acc[rtl][ct] = __builtin_amdgcn_mfma_f32_16x16x32_f16(ah[rtl], bh[ct], acc[rtl][ct], 0, 0, 0);
    }
    __syncthreads();   // last B reads done; B region becomes overlays

    float* redv1 = (float*)smem;            // [4][32]
    float* redv2 = (float*)(smem + 512);
    int*   redi1 = (int*)(smem + 1024);
    int*   qsh   = (int*)(smem + 1536);
    float* wsumx = (float*)(smem + 1664);

    // ---- per-row best1/best2 within wave (codes cg*128..+127) ----
    #pragma unroll
    for (int rtl = 0; rtl < 2; ++rtl) {
        #pragma unroll
        for (int r = 0; r < 4; ++r) {
            float v1 = 3.4e38f, v2 = 3.4e38f; int i1 = 0;
            #pragma unroll
            for (int ct = 0; ct < 8; ++ct) {
                int code = (cg * 8 + ct) * 16 + l15;
                float dist = fmaf(-2.f, acc[rtl][ct][r], ws[code]);
                if (dist < v1) { v2 = v1; v1 = dist; i1 = code; }
                else if (dist < v2) v2 = dist;
            }
            #pragma unroll
            for (int off = 1; off < 16; off <<= 1) {
                float ov1 = __shfl_xor(v1, off, 64);
                int   oi1 = __shfl_xor(i1, off, 64);
                float ov2 = __shfl_xor(v2, off, 64);
                float nv2 = fminf(fmaxf(v1, ov1), fminf(v2, ov2));
                if (ov1 < v1 || (ov1 == v1 && oi1 < i1)) { v1 = ov1; i1 = oi1; }
                v2 = nv2;
            }
            if (l15 == 0) {
                int idx = cg * 32 + rtl * 16 + l4 * 4 + r;
                redv1[idx] = v1; redi1[idx] = i1; redv2[idx] = v2;
            }
        }
    }
    __syncthreads();

    float dist_part = 0.f;
    if (tid < QBM) {
        const int row = tid;
        float v1 = redv1[row]; int i1 = redi1[row]; float v2 = redv2[row];
        #pragma unroll
        for (int s = 1; s < 4; ++s) {
            float ov1 = redv1[s * 32 + row]; int oi1 = redi1[s * 32 + row]; float ov2 = redv2[s * 32 + row];
            float nv2 = fminf(fmaxf(v1, ov1), fminf(v2, ov2));
            if (ov1 < v1 || (ov1 == v1 && oi1 < i1)) { v1 = ov1; i1 = oi1; }
            v2 = nv2;
        }
        qsh[row] = i1;
        out[OUT_Q_OFF + n0 + row] = (float)i1;
        if (v2 - v1 <= MARGIN) {
            int idx = atomicAdd((int*)ws + WS_CNT_I, 1);
            ((int*)ws)[WS_LIST_I + idx] = n0 + row;
        }
        dist_part = v1;
    }
    float dv = dist_part;
    #pragma unroll
    for (int off = 32; off; off >>= 1) dv += __shfl_down(dv, off, 64);
    if (tid == 0) ws[WS_DIST + blk] = dv;

    float xv = x2local;
    #pragma unroll
    for (int off = 32; off; off >>= 1) xv += __shfl_down(xv, off, 64);
    if (lane == 0) wsumx[wave] = xv;
    __syncthreads();
    if (tid == 0) ws[WS_X2 + blk] = wsumx[0] + wsumx[1] + wsumx[2] + wsumx[3];

    // ---- x_e write (approx q; exact pass fixes flagged rows) ----
    {
        const int row = tid & 31;
        const int dg  = tid >> 5;      // 0..7 -> d range dg*32..+31
        const int q   = qsh[row];
        const float* crow = lut + (size_t)q * DIM;
        float* ob = out + (size_t)b * (DIM * HW) + hw0 + row;
        #pragma unroll 4
        for (int i = 0; i < 8; ++i) {
            int d0 = dg * 32 + i * 4;
            float4 c = *(const float4*)(crow + d0);
            ob[(size_t)(d0 + 0) * HW] = c.x;
            ob[(size_t)(d0 + 1) * HW] = c.y;
            ob[(size_t)(d0 + 2) * HW] = c.z;
            ob[(size_t)(d0 + 3) * HW] = c.w;
        }
    }
}

// exact fp32 recheck of flagged rows (sequential-fmaf form, np-matching per R6-R13)
__global__ void exact_kernel(const float* __restrict__ x, const float* __restrict__ lut,
                             float* __restrict__ out, const float* __restrict__ ws) {
    __shared__ float xr[DIM];
    __shared__ float rv[256];
    __shared__ int   ri[256];
    const int cnt = ((const int*)ws)[WS_CNT_I];
    const int* list = (const int*)ws + WS_LIST_I;
    const int tid = threadIdx.x;
    for (int ii = blockIdx.x; ii < cnt; ii += gridDim.x) {
        const int row = list[ii];
        const int b = row >> 10, hw = row & 1023;
        __syncthreads();
        xr[tid] = x[(size_t)b * (DIM * HW) + (size_t)tid * HW + hw];
        __syncthreads();
        float bv = 3.4e38f; int bi = 0;
        #pragma unroll
        for (int k2 = 0; k2 < 2; ++k2) {
            int k = tid + k2 * 256;
            const float* cr = lut + (size_t)k * DIM;
            float dot = 0.f;
            for (int d = 0; d < DIM; ++d) dot = fmaf(xr[d], cr[d], dot);
            float dist = fmaf(-2.f, dot, ws[k]);
            if (dist < bv || (dist == bv && k < bi)) { bv = dist; bi = k; }
        }
        rv[tid] = bv; ri[tid] = bi;
        __syncthreads();
        for (int s = 128; s; s >>= 1) {
            if (tid < s) {
                float ov = rv[tid + s]; int oi = ri[tid + s];
                if (ov < rv[tid] || (ov == rv[tid] && oi < ri[tid])) {
                    rv[tid] = ov; ri[tid] = oi;
                }
            }
            __syncthreads();
        }
        const int q = ri[0];
        if (tid == 0) out[OUT_Q_OFF + row] = (float)q;
        out[(size_t)b * (DIM * HW) + (size_t)tid * HW + hw] = lut[(size_t)q * DIM + tid];
    }
}

__global__ void loss_kernel(float* __restrict__ out, const float* __restrict__ ws) {
    __shared__ float wsum[4];
    int tid = threadIdx.x;
    float s = 0.f;
    for (int i = tid; i < 4096; i += 256) s += ws[WS_DIST + i];   // dist[512,2560) + x2[2560,4608)
    #pragma unroll
    for (int off = 32; off; off >>= 1) s += __shfl_down(s, off, 64);
    if ((tid & 63) == 0) wsum[tid >> 6] = s;
    __syncthreads();
    if (tid == 0) {
        float total = wsum[0] + wsum[1] + wsum[2] + wsum[3];
        out[OUT_LOSS_OFF] = total * (1.25f / 16777216.f);
    }
}

extern "C" void kernel_launch(void* const* d_in, const int* in_sizes, int n_in,
                              void* d_out, int out_size, void* d_ws, size_t ws_size,
                              hipStream_t stream) {
    const float* x   = (const float*)d_in[0];
    const float* lut = (const float*)d_in[1];
    float* out = (float*)d_out;
    float* ws  = (float*)d_ws;

    (void)hipFuncSetAttribute((const void*)vq_kernel,
                              hipFuncAttributeMaxDynamicSharedMemorySize, VQ_LDS);

    c2_kernel<<<1, 256, 0, stream>>>(lut, ws);
    lutprep_kernel<<<64, 256, 0, stream>>>(lut, ws);
    vq_kernel<<<NBLK, NT, VQ_LDS, stream>>>(x, lut, out, ws);
    exact_kernel<<<2048, 256, 0, stream>>>(x, lut, out, ws);
    loss_kernel<<<1, 256, 0, stream>>>(out, ws);
}